// Round 6
// baseline (214.464 us; speedup 1.0000x reference)
//
#include <hip/hip_runtime.h>
#include <hip/hip_fp16.h>
#include <math.h>

#define FL     8192
#define BS     4096      // block step = FL/2
#define CD     16
#define BATCH  32
#define SEQ    262144
#define NPAIR  32        // 64 blocks -> 32 pairs

// LDS swizzle for 4-byte (half2) elements: bank = i%32; XOR low5 with bits 5..9.
// Every pass's wave64 access hits each bank exactly 2x (free, m136).
__device__ __forceinline__ int SW(int i){ return i ^ ((i >> 5) & 31); }

__device__ __forceinline__ float2 cadd(float2 a, float2 b){ return make_float2(a.x+b.x, a.y+b.y); }
__device__ __forceinline__ float2 csub(float2 a, float2 b){ return make_float2(a.x-b.x, a.y-b.y); }
__device__ __forceinline__ float2 cmul(float2 a, float2 b){ return make_float2(a.x*b.x - a.y*b.y, a.x*b.y + a.y*b.x); }
// a * (c + i s)
__device__ __forceinline__ float2 mri(float2 a, float c, float s){ return make_float2(a.x*c - a.y*s, a.x*s + a.y*c); }

// fp16 LDS staging helpers
__device__ __forceinline__ void sth(__half2* buf, int i, float2 v){ buf[SW(i)] = __floats2half2_rn(v.x, v.y); }
__device__ __forceinline__ float2 ldh(const __half2* buf, int i){ return __half22float2(buf[SW(i)]); }

// Digit-reversed bin stored at position p after DIF passes
// A(R16,s512), B(R16,s32), C(R2,s16), D(R16,s1):
// k = qA + 16*qB + 256*qC + 512*qD ; p = 512*qA + 32*qB + 16*qC + qD
__device__ __forceinline__ int bin_of_pos(int p){
    return ((p>>9)&15) | (((p>>5)&15)<<4) | (((p>>4)&1)<<8) | ((p&15)<<9);
}

// ---------------------------------------------------------------------------
// In-register 16-point DFT, natural order in/out, 4x4 Cooley-Tukey.
// INV: conjugate (inverse, unnormalized). HALF: inputs d[8..15] are zero.
// ---------------------------------------------------------------------------
template<bool INV, bool HALF>
__device__ __forceinline__ void dft16(float2* d){
    constexpr float sgn = INV ? 1.f : -1.f;          // e^{sgn*i*2pi*k/16}
    constexpr float C1 = 0.923879532511287f;          // cos(pi/8)
    constexpr float S1 = 0.382683432365090f;          // sin(pi/8)
    constexpr float R  = 0.707106781186548f;
    float2 u[16];
#pragma unroll
    for (int b=0;b<4;++b){
        const float2 a0=d[b], a1=d[4+b];
        if (HALF){
            const float2 ja1 = make_float2(-sgn*a1.y, sgn*a1.x);
            u[4*b+0]=cadd(a0,a1);
            u[4*b+1]=cadd(a0,ja1);
            u[4*b+2]=csub(a0,a1);
            u[4*b+3]=csub(a0,ja1);
        } else {
            const float2 a2=d[8+b], a3=d[12+b];
            const float2 s0=cadd(a0,a2), s1=csub(a0,a2);
            const float2 s2=cadd(a1,a3), s3=csub(a1,a3);
            const float2 js3 = make_float2(-sgn*s3.y, sgn*s3.x);
            u[4*b+0]=cadd(s0,s2);
            u[4*b+1]=cadd(s1,js3);
            u[4*b+2]=csub(s0,s2);
            u[4*b+3]=csub(s1,js3);
        }
    }
    u[4+1] = mri(u[4+1],  C1, sgn*S1);
    u[4+2] = mri(u[4+2],  R,  sgn*R );
    u[4+3] = mri(u[4+3],  S1, sgn*C1);
    u[8+1] = mri(u[8+1],  R,  sgn*R );
    u[8+2] = mri(u[8+2],  0.f, sgn);
    u[8+3] = mri(u[8+3], -R,  sgn*R );
    u[12+1]= mri(u[12+1], S1, sgn*C1);
    u[12+2]= mri(u[12+2],-R,  sgn*R );
    u[12+3]= mri(u[12+3],-C1,-sgn*S1);
#pragma unroll
    for (int c=0;c<4;++c){
        const float2 a0=u[c], a1=u[4+c], a2=u[8+c], a3=u[12+c];
        const float2 s0=cadd(a0,a2), s1=csub(a0,a2);
        const float2 s2=cadd(a1,a3), s3=csub(a1,a3);
        const float2 js3 = make_float2(-sgn*s3.y, sgn*s3.x);
        d[c+0] =cadd(s0,s2);
        d[c+4] =cadd(s1,js3);
        d[c+8] =csub(s0,s2);
        d[c+12]=csub(s1,js3);
    }
}

// chained twiddle: d[q] *= w1^q, q=1..15
__device__ __forceinline__ void twiddle_chain(float2* d, float2 w1){
    float2 wq = w1;
    d[1] = cmul(d[1], wq);
#pragma unroll
    for (int q=2;q<16;++q){ wq = cmul(wq, w1); d[q] = cmul(d[q], wq); }
}

// ---------------------------------------------------------------------------
// Heff per (batch, position): Heff[f] = (H[f] + conj(H[(N-f)%N]))/2 / N,
// stored at digit-reversed position p.
// ---------------------------------------------------------------------------
__global__ void h_kernel(const float* __restrict__ c,  const float* __restrict__ Wf,
                         const float* __restrict__ bfv, const float* __restrict__ Wp,
                         const float* __restrict__ bpv, float2* __restrict__ H){
    const int p = blockIdx.x*256 + threadIdx.x;
    const int b = blockIdx.y;
    const int f = bin_of_pos(p);
    const int g = (FL - f) & (FL - 1);
    float amf = bfv[f], apf = bpv[f], amg = bfv[g], apg = bpv[g];
#pragma unroll
    for (int i=0;i<CD;++i){
        const float cv = c[b*CD + i];
        amf += cv * Wf[f*CD + i];
        apf += cv * Wp[f*CD + i];
        amg += cv * Wf[g*CD + i];
        apg += cv * Wp[g*CD + i];
    }
    const float magf = 1.f/(1.f+__expf(-amf));
    const float magg = 1.f/(1.f+__expf(-amg));
    float sf, cf2, sg, cg2;
    __sincosf(apf, &sf, &cf2);
    __sincosf(apg, &sg, &cg2);
    const float scale = 0.5f / (float)FL;
    H[(size_t)b*FL + p] = make_float2((magf*cf2 + magg*cg2)*scale,
                                      (magf*sf  - magg*sg )*scale);
}

// ---------------------------------------------------------------------------
// One WG (512 thr) per (block-pair, batch). Register-resident mixed-radix FFT
// with fp16 LDS staging (32 KiB -> 4 WG/CU):
// A: global->reg, DFT16(half), tw W_8192^{jq}, ->LDS   (stride 512)
// B: LDS DFT16 + tw W_512^{jq}                          (stride 32)
// C: radix-2 + tw W_32^j                                (stride 16)
// D: DFT16 x Heff x IDFT16 fused                        (stride 1)
// C',B': mirrors with conj twiddles
// A': LDS->reg, conj tw, IDFT16, overlap-add -> global
// ---------------------------------------------------------------------------
__global__ __launch_bounds__(512, 8) void fft_kernel(const float*  __restrict__ x,
                                                     const float2* __restrict__ H,
                                                     float* __restrict__ out){
    extern __shared__ __half2 buf[];     // 8192 * 4B = 32 KiB
    const int t  = threadIdx.x;
    const int pr = blockIdx.x;
    const int b  = blockIdx.y;
    const float* xb = x + (size_t)b*SEQ;
    const int s0 = 2*pr*BS - (FL-1);
    const float TWO_PI = 6.28318530717958647692f;

    float2 d[16];

    constexpr float CT[16] = { 1.f, 0.980785280403230f, 0.923879532511287f, 0.831469612302545f,
                               0.707106781186548f, 0.555570233019602f, 0.382683432365090f, 0.195090322016128f,
                               0.f,-0.195090322016128f,-0.382683432365090f,-0.555570233019602f,
                              -0.707106781186548f,-0.831469612302545f,-0.923879532511287f,-0.980785280403230f };
    constexpr float ST[16] = { 0.f, 0.195090322016128f, 0.382683432365090f, 0.555570233019602f,
                               0.707106781186548f, 0.831469612302545f, 0.923879532511287f, 0.980785280403230f,
                               1.f, 0.980785280403230f, 0.923879532511287f, 0.831469612302545f,
                               0.707106781186548f, 0.555570233019602f, 0.382683432365090f, 0.195090322016128f };

    // ---- Pass A: radix-16, stride 512 (input half-zero) ----
    {
        const int j = t;
#pragma unroll
        for (int m=0;m<8;++m){
            const int k  = j + 512*m;          // < 4096 always
            const int ua = s0 + k, ub = ua + BS;
            float va = (ua >= 0) ? xb[ua] : 0.f;
            float vb = (ub >= 0) ? xb[ub] : 0.f;
            d[m] = make_float2(va, vb);
        }
        dft16<false,true>(d);
        float snv, csv; __sincosf(-TWO_PI * (float)j / 8192.f, &snv, &csv);
        twiddle_chain(d, make_float2(csv, snv));
#pragma unroll
        for (int q=0;q<16;++q) sth(buf, j + 512*q, d[q]);
    }
    __syncthreads();

    // ---- Pass B: radix-16, stride 32 ----
    {
        const int base = ((t>>5)<<9) + (t&31);
        const int j = t&31;
#pragma unroll
        for (int m=0;m<16;++m) d[m] = ldh(buf, base + 32*m);
        dft16<false,false>(d);
        float snv, csv; __sincosf(-TWO_PI * (float)j / 512.f, &snv, &csv);
        twiddle_chain(d, make_float2(csv, snv));
#pragma unroll
        for (int q=0;q<16;++q) sth(buf, base + 32*q, d[q]);
    }
    __syncthreads();

    // ---- Pass C: radix-2, stride 16, tw W_32^j on odd output ----
    {
        const int r = t&1, base = 32*(t>>1) + 8*r;
#pragma unroll
        for (int jj=0;jj<8;++jj){
            const int i0 = base + jj;
            const float2 a = ldh(buf, i0), bb = ldh(buf, i0+16);
            const float ck = r ? CT[jj+8] : CT[jj];
            const float sk = r ? ST[jj+8] : ST[jj];
            sth(buf, i0,    cadd(a,bb));
            sth(buf, i0+16, mri(csub(a,bb), ck, -sk));
        }
    }
    __syncthreads();

    // ---- Pass D: DFT16 x Heff x IDFT16, contiguous 16-block ----
    {
        const int base = t<<4;
#pragma unroll
        for (int i=0;i<16;++i) d[i] = ldh(buf, base+i);
        dft16<false,false>(d);
        const float4* H4 = reinterpret_cast<const float4*>(H + (size_t)b*FL + base);
#pragma unroll
        for (int q=0;q<8;++q){
            const float4 hv = H4[q];
            d[2*q]   = cmul(d[2*q],   make_float2(hv.x, hv.y));
            d[2*q+1] = cmul(d[2*q+1], make_float2(hv.z, hv.w));
        }
        dft16<true,false>(d);
#pragma unroll
        for (int i=0;i<16;++i) sth(buf, base+i, d[i]);
    }
    __syncthreads();

    // ---- Pass C': inverse radix-2, stride 16, conj tw before butterfly ----
    {
        const int r = t&1, base = 32*(t>>1) + 8*r;
#pragma unroll
        for (int jj=0;jj<8;++jj){
            const int i0 = base + jj;
            const float2 a = ldh(buf, i0), bb = ldh(buf, i0+16);
            const float ck = r ? CT[jj+8] : CT[jj];
            const float sk = r ? ST[jj+8] : ST[jj];
            const float2 tb = mri(bb, ck, sk);
            sth(buf, i0,    cadd(a,tb));
            sth(buf, i0+16, csub(a,tb));
        }
    }
    __syncthreads();

    // ---- Pass B': inverse radix-16, stride 32 ----
    {
        const int base = ((t>>5)<<9) + (t&31);
        const int j = t&31;
#pragma unroll
        for (int q=0;q<16;++q) d[q] = ldh(buf, base + 32*q);
        float snv, csv; __sincosf(TWO_PI * (float)j / 512.f, &snv, &csv);
        twiddle_chain(d, make_float2(csv, snv));
        dft16<true,false>(d);
#pragma unroll
        for (int m=0;m<16;++m) sth(buf, base + 32*m, d[m]);
    }
    __syncthreads();

    // ---- Pass A': inverse radix-16, stride 512 + overlap-add to global ----
    {
        const int j = t;
#pragma unroll
        for (int q=0;q<16;++q) d[q] = ldh(buf, j + 512*q);
        float snv, csv; __sincosf(TWO_PI * (float)j / 8192.f, &snv, &csv);
        twiddle_chain(d, make_float2(csv, snv));
        dft16<true,false>(d);
        // d[m] = y[time j + 512*m]; Re -> block a, Im -> block b
        float* ob = out + (size_t)b*SEQ;
        const int pa = 2*pr*BS;
#pragma unroll
        for (int mm=0;mm<8;++mm){
            const int klo = j + 512*mm;
            atomicAdd(&ob[pa+klo], d[mm].x);                 // even span (2 writers)
            ob[pa+BS+klo] = d[mm+8].x + d[mm].y;             // odd span (sole writer)
            const int p3 = pa + 2*BS + klo;
            if (p3 < SEQ) atomicAdd(&ob[p3], d[mm+8].y);     // even span (2 writers)
        }
    }
}

// ---------------------------------------------------------------------------
extern "C" void kernel_launch(void* const* d_in, const int* in_sizes, int n_in,
                              void* d_out, int out_size, void* d_ws, size_t ws_size,
                              hipStream_t stream) {
    const float* x   = (const float*)d_in[0];
    const float* c   = (const float*)d_in[1];
    const float* Wf  = (const float*)d_in[2];
    const float* bfv = (const float*)d_in[3];
    const float* Wp  = (const float*)d_in[4];
    const float* bpv = (const float*)d_in[5];

    float*  out = (float*)d_out;
    float2* H   = (float2*)d_ws;                      // BATCH*FL*8B = 2 MiB

    hipMemsetAsync(d_out, 0, (size_t)out_size*sizeof(float), stream);
    h_kernel<<<dim3(FL/256, BATCH), 256, 0, stream>>>(c, Wf, bfv, Wp, bpv, H);
    fft_kernel<<<dim3(NPAIR, BATCH), 512, FL*sizeof(__half2), stream>>>(x, H, out);
}

// Round 7
// 163.554 us; speedup vs baseline: 1.3113x; 1.3113x over previous
//
#include <hip/hip_runtime.h>
#include <hip/hip_fp16.h>
#include <math.h>

#define FL     8192
#define BS     4096      // block step = FL/2
#define CD     16
#define BATCH  32
#define SEQ    262144
#define NPAIR  32        // 64 blocks -> 32 pairs

// LDS swizzle for 4-byte (half2) elements: bank = i%32; XOR low5 with bits 5..9.
__device__ __forceinline__ int SW(int i){ return i ^ ((i >> 5) & 31); }

__device__ __forceinline__ float2 cadd(float2 a, float2 b){ return make_float2(a.x+b.x, a.y+b.y); }
__device__ __forceinline__ float2 csub(float2 a, float2 b){ return make_float2(a.x-b.x, a.y-b.y); }
__device__ __forceinline__ float2 cmul(float2 a, float2 b){ return make_float2(a.x*b.x - a.y*b.y, a.x*b.y + a.y*b.x); }
// a * (c + i s)
__device__ __forceinline__ float2 mri(float2 a, float c, float s){ return make_float2(a.x*c - a.y*s, a.x*s + a.y*c); }

// fp16 LDS staging helpers
__device__ __forceinline__ void sth(__half2* buf, int i, float2 v){ buf[SW(i)] = __floats2half2_rn(v.x, v.y); }
__device__ __forceinline__ float2 ldh(const __half2* buf, int i){ return __half22float2(buf[SW(i)]); }

// Digit-reversed bin stored at position p after DIF passes
// A(R16,s512), B(R16,s32), C(R2,s16), D(R16,s1):
// k = qA + 16*qB + 256*qC + 512*qD ; p = 512*qA + 32*qB + 16*qC + qD
__device__ __forceinline__ int bin_of_pos(int p){
    return ((p>>9)&15) | (((p>>5)&15)<<4) | (((p>>4)&1)<<8) | ((p&15)<<9);
}

// ---------------------------------------------------------------------------
// In-register 16-point DFT, natural order in/out, 4x4 Cooley-Tukey.
// INV: conjugate (inverse, unnormalized). HALF: inputs d[8..15] are zero.
// ---------------------------------------------------------------------------
template<bool INV, bool HALF>
__device__ __forceinline__ void dft16(float2* d){
    constexpr float sgn = INV ? 1.f : -1.f;          // e^{sgn*i*2pi*k/16}
    constexpr float C1 = 0.923879532511287f;          // cos(pi/8)
    constexpr float S1 = 0.382683432365090f;          // sin(pi/8)
    constexpr float R  = 0.707106781186548f;
    float2 u[16];
#pragma unroll
    for (int b=0;b<4;++b){
        const float2 a0=d[b], a1=d[4+b];
        if (HALF){
            const float2 ja1 = make_float2(-sgn*a1.y, sgn*a1.x);
            u[4*b+0]=cadd(a0,a1);
            u[4*b+1]=cadd(a0,ja1);
            u[4*b+2]=csub(a0,a1);
            u[4*b+3]=csub(a0,ja1);
        } else {
            const float2 a2=d[8+b], a3=d[12+b];
            const float2 s0=cadd(a0,a2), s1=csub(a0,a2);
            const float2 s2=cadd(a1,a3), s3=csub(a1,a3);
            const float2 js3 = make_float2(-sgn*s3.y, sgn*s3.x);
            u[4*b+0]=cadd(s0,s2);
            u[4*b+1]=cadd(s1,js3);
            u[4*b+2]=csub(s0,s2);
            u[4*b+3]=csub(s1,js3);
        }
    }
    u[4+1] = mri(u[4+1],  C1, sgn*S1);
    u[4+2] = mri(u[4+2],  R,  sgn*R );
    u[4+3] = mri(u[4+3],  S1, sgn*C1);
    u[8+1] = mri(u[8+1],  R,  sgn*R );
    u[8+2] = mri(u[8+2],  0.f, sgn);
    u[8+3] = mri(u[8+3], -R,  sgn*R );
    u[12+1]= mri(u[12+1], S1, sgn*C1);
    u[12+2]= mri(u[12+2],-R,  sgn*R );
    u[12+3]= mri(u[12+3],-C1,-sgn*S1);
#pragma unroll
    for (int c=0;c<4;++c){
        const float2 a0=u[c], a1=u[4+c], a2=u[8+c], a3=u[12+c];
        const float2 s0=cadd(a0,a2), s1=csub(a0,a2);
        const float2 s2=cadd(a1,a3), s3=csub(a1,a3);
        const float2 js3 = make_float2(-sgn*s3.y, sgn*s3.x);
        d[c+0] =cadd(s0,s2);
        d[c+4] =cadd(s1,js3);
        d[c+8] =csub(s0,s2);
        d[c+12]=csub(s1,js3);
    }
}

// chained twiddle: d[q] *= w1^q, q=1..15
__device__ __forceinline__ void twiddle_chain(float2* d, float2 w1){
    float2 wq = w1;
    d[1] = cmul(d[1], wq);
#pragma unroll
    for (int q=2;q<16;++q){ wq = cmul(wq, w1); d[q] = cmul(d[q], wq); }
}

// ---------------------------------------------------------------------------
// Heff per (batch, position): Heff[f] = (H[f] + conj(H[(N-f)%N]))/2 / N,
// stored at digit-reversed position p.
// ---------------------------------------------------------------------------
__global__ void h_kernel(const float* __restrict__ c,  const float* __restrict__ Wf,
                         const float* __restrict__ bfv, const float* __restrict__ Wp,
                         const float* __restrict__ bpv, float2* __restrict__ H){
    const int p = blockIdx.x*256 + threadIdx.x;
    const int b = blockIdx.y;
    const int f = bin_of_pos(p);
    const int g = (FL - f) & (FL - 1);
    float amf = bfv[f], apf = bpv[f], amg = bfv[g], apg = bpv[g];
#pragma unroll
    for (int i=0;i<CD;++i){
        const float cv = c[b*CD + i];
        amf += cv * Wf[f*CD + i];
        apf += cv * Wp[f*CD + i];
        amg += cv * Wf[g*CD + i];
        apg += cv * Wp[g*CD + i];
    }
    const float magf = 1.f/(1.f+__expf(-amf));
    const float magg = 1.f/(1.f+__expf(-amg));
    float sf, cf2, sg, cg2;
    __sincosf(apf, &sf, &cf2);
    __sincosf(apg, &sg, &cg2);
    const float scale = 0.5f / (float)FL;
    H[(size_t)b*FL + p] = make_float2((magf*cf2 + magg*cg2)*scale,
                                      (magf*sf  - magg*sg )*scale);
}

// ---------------------------------------------------------------------------
// One WG (512 thr) per (block-pair, batch). Register-resident mixed-radix FFT
// with fp16 LDS staging (32 KiB). launch_bounds min-waves=6 -> VGPR budget ~85
// so the natural 64-VGPR allocation fits WITHOUT spilling (r6 lesson: 8 forced
// 32 VGPR + 290 MB scratch traffic). Final output goes through LDS once more
// for fully coalesced global writes.
// ---------------------------------------------------------------------------
__global__ __launch_bounds__(512, 6) void fft_kernel(const float*  __restrict__ x,
                                                     const float2* __restrict__ H,
                                                     float* __restrict__ out){
    extern __shared__ __half2 buf[];     // 8192 * 4B = 32 KiB
    const int t  = threadIdx.x;
    const int pr = blockIdx.x;
    const int b  = blockIdx.y;
    const float* xb = x + (size_t)b*SEQ;
    const int s0 = 2*pr*BS - (FL-1);
    const float TWO_PI = 6.28318530717958647692f;

    float2 d[16];

    constexpr float CT[16] = { 1.f, 0.980785280403230f, 0.923879532511287f, 0.831469612302545f,
                               0.707106781186548f, 0.555570233019602f, 0.382683432365090f, 0.195090322016128f,
                               0.f,-0.195090322016128f,-0.382683432365090f,-0.555570233019602f,
                              -0.707106781186548f,-0.831469612302545f,-0.923879532511287f,-0.980785280403230f };
    constexpr float ST[16] = { 0.f, 0.195090322016128f, 0.382683432365090f, 0.555570233019602f,
                               0.707106781186548f, 0.831469612302545f, 0.923879532511287f, 0.980785280403230f,
                               1.f, 0.980785280403230f, 0.923879532511287f, 0.831469612302545f,
                               0.707106781186548f, 0.555570233019602f, 0.382683432365090f, 0.195090322016128f };

    // ---- Pass A: radix-16, stride 512 (input half-zero) ----
    {
        const int j = t;
#pragma unroll
        for (int m=0;m<8;++m){
            const int k  = j + 512*m;          // < 4096 always
            const int ua = s0 + k, ub = ua + BS;
            float va = (ua >= 0) ? xb[ua] : 0.f;
            float vb = (ub >= 0) ? xb[ub] : 0.f;
            d[m] = make_float2(va, vb);
        }
        dft16<false,true>(d);
        float snv, csv; __sincosf(-TWO_PI * (float)j / 8192.f, &snv, &csv);
        twiddle_chain(d, make_float2(csv, snv));
#pragma unroll
        for (int q=0;q<16;++q) sth(buf, j + 512*q, d[q]);
    }
    __syncthreads();

    // ---- Pass B: radix-16, stride 32 ----
    {
        const int base = ((t>>5)<<9) + (t&31);
        const int j = t&31;
#pragma unroll
        for (int m=0;m<16;++m) d[m] = ldh(buf, base + 32*m);
        dft16<false,false>(d);
        float snv, csv; __sincosf(-TWO_PI * (float)j / 512.f, &snv, &csv);
        twiddle_chain(d, make_float2(csv, snv));
#pragma unroll
        for (int q=0;q<16;++q) sth(buf, base + 32*q, d[q]);
    }
    __syncthreads();

    // ---- Pass C: radix-2, stride 16, tw W_32^j on odd output ----
    {
        const int r = t&1, base = 32*(t>>1) + 8*r;
#pragma unroll
        for (int jj=0;jj<8;++jj){
            const int i0 = base + jj;
            const float2 a = ldh(buf, i0), bb = ldh(buf, i0+16);
            const float ck = r ? CT[jj+8] : CT[jj];
            const float sk = r ? ST[jj+8] : ST[jj];
            sth(buf, i0,    cadd(a,bb));
            sth(buf, i0+16, mri(csub(a,bb), ck, -sk));
        }
    }
    __syncthreads();

    // ---- Pass D: DFT16 x Heff x IDFT16, contiguous 16-block ----
    {
        const int base = t<<4;
#pragma unroll
        for (int i=0;i<16;++i) d[i] = ldh(buf, base+i);
        dft16<false,false>(d);
        const float4* H4 = reinterpret_cast<const float4*>(H + (size_t)b*FL + base);
#pragma unroll
        for (int q=0;q<8;++q){
            const float4 hv = H4[q];
            d[2*q]   = cmul(d[2*q],   make_float2(hv.x, hv.y));
            d[2*q+1] = cmul(d[2*q+1], make_float2(hv.z, hv.w));
        }
        dft16<true,false>(d);
#pragma unroll
        for (int i=0;i<16;++i) sth(buf, base+i, d[i]);
    }
    __syncthreads();

    // ---- Pass C': inverse radix-2, stride 16, conj tw before butterfly ----
    {
        const int r = t&1, base = 32*(t>>1) + 8*r;
#pragma unroll
        for (int jj=0;jj<8;++jj){
            const int i0 = base + jj;
            const float2 a = ldh(buf, i0), bb = ldh(buf, i0+16);
            const float ck = r ? CT[jj+8] : CT[jj];
            const float sk = r ? ST[jj+8] : ST[jj];
            const float2 tb = mri(bb, ck, sk);
            sth(buf, i0,    cadd(a,tb));
            sth(buf, i0+16, csub(a,tb));
        }
    }
    __syncthreads();

    // ---- Pass B': inverse radix-16, stride 32 ----
    {
        const int base = ((t>>5)<<9) + (t&31);
        const int j = t&31;
#pragma unroll
        for (int q=0;q<16;++q) d[q] = ldh(buf, base + 32*q);
        float snv, csv; __sincosf(TWO_PI * (float)j / 512.f, &snv, &csv);
        twiddle_chain(d, make_float2(csv, snv));
        dft16<true,false>(d);
#pragma unroll
        for (int m=0;m<16;++m) sth(buf, base + 32*m, d[m]);
    }
    __syncthreads();

    // ---- Pass A': inverse radix-16, stride 512; park time samples in LDS ----
    {
        const int j = t;
#pragma unroll
        for (int q=0;q<16;++q) d[q] = ldh(buf, j + 512*q);
        float snv, csv; __sincosf(TWO_PI * (float)j / 8192.f, &snv, &csv);
        twiddle_chain(d, make_float2(csv, snv));
        dft16<true,false>(d);
    }
    __syncthreads();   // all spec reads done before overwriting with time data
    {
        const int j = t;
#pragma unroll
        for (int m=0;m<16;++m) sth(buf, j + 512*m, d[m]);   // y[time j+512m]
    }
    __syncthreads();

    // ---- Output phase: fully coalesced overlap-add ----
    // klo = t + 512*jj -> lanes 4B-contiguous in every stream.
    {
        float* ob = out + (size_t)b*SEQ;
        const int pa = 2*pr*BS;
#pragma unroll
        for (int jj=0;jj<8;++jj){
            const int klo = t + 512*jj;                      // 0..4095
            const float2 wlo = ldh(buf, klo);                // y[klo]
            const float2 whi = ldh(buf, klo + BS);           // y[klo+4096]
            atomicAdd(&ob[pa+klo], wlo.x);                   // even span (2 writers)
            ob[pa+BS+klo] = whi.x + wlo.y;                   // odd span (sole writer)
            const int p3 = pa + 2*BS + klo;
            if (p3 < SEQ) atomicAdd(&ob[p3], whi.y);         // even span (2 writers)
        }
    }
}

// ---------------------------------------------------------------------------
extern "C" void kernel_launch(void* const* d_in, const int* in_sizes, int n_in,
                              void* d_out, int out_size, void* d_ws, size_t ws_size,
                              hipStream_t stream) {
    const float* x   = (const float*)d_in[0];
    const float* c   = (const float*)d_in[1];
    const float* Wf  = (const float*)d_in[2];
    const float* bfv = (const float*)d_in[3];
    const float* Wp  = (const float*)d_in[4];
    const float* bpv = (const float*)d_in[5];

    float*  out = (float*)d_out;
    float2* H   = (float2*)d_ws;                      // BATCH*FL*8B = 2 MiB

    hipMemsetAsync(d_out, 0, (size_t)out_size*sizeof(float), stream);
    h_kernel<<<dim3(FL/256, BATCH), 256, 0, stream>>>(c, Wf, bfv, Wp, bpv, H);
    fft_kernel<<<dim3(NPAIR, BATCH), 512, FL*sizeof(__half2), stream>>>(x, H, out);
}

// Round 8
// 98.588 us; speedup vs baseline: 2.1754x; 1.6590x over previous
//
#include <hip/hip_runtime.h>
#include <hip/hip_fp16.h>
#include <math.h>

#define FL     8192
#define BS     4096      // block step = FL/2
#define CD     16
#define BATCH  32
#define SEQ    262144
#define NPAIR  32        // 64 blocks -> 32 pairs

// LDS swizzle for 4-byte (half2) elements: bank = i%32; XOR low5 with bits 5..9.
// Verified per-pass: every wave64 access in A/B/C/D/out hits each bank exactly 2x (free).
__device__ __forceinline__ int SW(int i){ return i ^ ((i >> 5) & 31); }

__device__ __forceinline__ float2 cadd(float2 a, float2 b){ return make_float2(a.x+b.x, a.y+b.y); }
__device__ __forceinline__ float2 csub(float2 a, float2 b){ return make_float2(a.x-b.x, a.y-b.y); }
__device__ __forceinline__ float2 cmul(float2 a, float2 b){ return make_float2(a.x*b.x - a.y*b.y, a.x*b.y + a.y*b.x); }
// a * (c + i s)
__device__ __forceinline__ float2 mri(float2 a, float c, float s){ return make_float2(a.x*c - a.y*s, a.x*s + a.y*c); }

// fp16 LDS staging helpers
__device__ __forceinline__ void sth(__half2* buf, int i, float2 v){ buf[SW(i)] = __floats2half2_rn(v.x, v.y); }
__device__ __forceinline__ float2 ldh(const __half2* buf, int i){ return __half22float2(buf[SW(i)]); }

// Digit-reversed bin stored at position p after DIF passes
// A(R16,s512), B(R16,s32), C(R2,s16), D(R16,s1):
// k = qA + 16*qB + 256*qC + 512*qD ; p = 512*qA + 32*qB + 16*qC + qD
__device__ __forceinline__ int bin_of_pos(int p){
    return ((p>>9)&15) | (((p>>5)&15)<<4) | (((p>>4)&1)<<8) | ((p&15)<<9);
}

// ---------------------------------------------------------------------------
// In-register 16-point DFT, natural order in/out, 4x4 Cooley-Tukey.
// INV: conjugate (inverse, unnormalized). HALF: inputs d[8..15] are zero.
// ---------------------------------------------------------------------------
template<bool INV, bool HALF>
__device__ __forceinline__ void dft16(float2* d){
    constexpr float sgn = INV ? 1.f : -1.f;          // e^{sgn*i*2pi*k/16}
    constexpr float C1 = 0.923879532511287f;          // cos(pi/8)
    constexpr float S1 = 0.382683432365090f;          // sin(pi/8)
    constexpr float R  = 0.707106781186548f;
    float2 u[16];
#pragma unroll
    for (int b=0;b<4;++b){
        const float2 a0=d[b], a1=d[4+b];
        if (HALF){
            const float2 ja1 = make_float2(-sgn*a1.y, sgn*a1.x);
            u[4*b+0]=cadd(a0,a1);
            u[4*b+1]=cadd(a0,ja1);
            u[4*b+2]=csub(a0,a1);
            u[4*b+3]=csub(a0,ja1);
        } else {
            const float2 a2=d[8+b], a3=d[12+b];
            const float2 s0=cadd(a0,a2), s1=csub(a0,a2);
            const float2 s2=cadd(a1,a3), s3=csub(a1,a3);
            const float2 js3 = make_float2(-sgn*s3.y, sgn*s3.x);
            u[4*b+0]=cadd(s0,s2);
            u[4*b+1]=cadd(s1,js3);
            u[4*b+2]=csub(s0,s2);
            u[4*b+3]=csub(s1,js3);
        }
    }
    u[4+1] = mri(u[4+1],  C1, sgn*S1);
    u[4+2] = mri(u[4+2],  R,  sgn*R );
    u[4+3] = mri(u[4+3],  S1, sgn*C1);
    u[8+1] = mri(u[8+1],  R,  sgn*R );
    u[8+2] = mri(u[8+2],  0.f, sgn);
    u[8+3] = mri(u[8+3], -R,  sgn*R );
    u[12+1]= mri(u[12+1], S1, sgn*C1);
    u[12+2]= mri(u[12+2],-R,  sgn*R );
    u[12+3]= mri(u[12+3],-C1,-sgn*S1);
#pragma unroll
    for (int c=0;c<4;++c){
        const float2 a0=u[c], a1=u[4+c], a2=u[8+c], a3=u[12+c];
        const float2 s0=cadd(a0,a2), s1=csub(a0,a2);
        const float2 s2=cadd(a1,a3), s3=csub(a1,a3);
        const float2 js3 = make_float2(-sgn*s3.y, sgn*s3.x);
        d[c+0] =cadd(s0,s2);
        d[c+4] =cadd(s1,js3);
        d[c+8] =csub(s0,s2);
        d[c+12]=csub(s1,js3);
    }
}

// chained twiddle: d[q] *= w1^q, q=1..15
__device__ __forceinline__ void twiddle_chain(float2* d, float2 w1){
    float2 wq = w1;
    d[1] = cmul(d[1], wq);
#pragma unroll
    for (int q=2;q<16;++q){ wq = cmul(wq, w1); d[q] = cmul(d[q], wq); }
}

// ---------------------------------------------------------------------------
// Heff per (batch, position): Heff[f] = (H[f] + conj(H[(N-f)%N]))/2 / N,
// stored at digit-reversed position p.
// ---------------------------------------------------------------------------
__global__ void h_kernel(const float* __restrict__ c,  const float* __restrict__ Wf,
                         const float* __restrict__ bfv, const float* __restrict__ Wp,
                         const float* __restrict__ bpv, float2* __restrict__ H){
    const int p = blockIdx.x*256 + threadIdx.x;
    const int b = blockIdx.y;
    const int f = bin_of_pos(p);
    const int g = (FL - f) & (FL - 1);
    float amf = bfv[f], apf = bpv[f], amg = bfv[g], apg = bpv[g];
#pragma unroll
    for (int i=0;i<CD;++i){
        const float cv = c[b*CD + i];
        amf += cv * Wf[f*CD + i];
        apf += cv * Wp[f*CD + i];
        amg += cv * Wf[g*CD + i];
        apg += cv * Wp[g*CD + i];
    }
    const float magf = 1.f/(1.f+__expf(-amf));
    const float magg = 1.f/(1.f+__expf(-amg));
    float sf, cf2, sg, cg2;
    __sincosf(apf, &sf, &cf2);
    __sincosf(apg, &sg, &cg2);
    const float scale = 0.5f / (float)FL;
    H[(size_t)b*FL + p] = make_float2((magf*cf2 + magg*cg2)*scale,
                                      (magf*sf  - magg*sg )*scale);
}

// ---------------------------------------------------------------------------
// One WG (512 thr) per (block-pair, batch). Register-resident mixed-radix FFT
// with fp16 LDS staging (32 KiB) and coalesced output.
// __launch_bounds__(512,4): r5-proven to yield 64 VGPR / ZERO spill. r6 (,8)
// forced 32 VGPR and r7 (,6) forced 40 VGPR -> 200-300 MB scratch traffic.
// At 64 VGPR the HW can still run 8 waves/SIMD; 32 KiB LDS allows 4 WG/CU.
// ---------------------------------------------------------------------------
__global__ __launch_bounds__(512, 4) void fft_kernel(const float*  __restrict__ x,
                                                     const float2* __restrict__ H,
                                                     float* __restrict__ out){
    extern __shared__ __half2 buf[];     // 8192 * 4B = 32 KiB
    const int t  = threadIdx.x;
    const int pr = blockIdx.x;
    const int b  = blockIdx.y;
    const float* xb = x + (size_t)b*SEQ;
    const int s0 = 2*pr*BS - (FL-1);
    const float TWO_PI = 6.28318530717958647692f;

    float2 d[16];

    constexpr float CT[16] = { 1.f, 0.980785280403230f, 0.923879532511287f, 0.831469612302545f,
                               0.707106781186548f, 0.555570233019602f, 0.382683432365090f, 0.195090322016128f,
                               0.f,-0.195090322016128f,-0.382683432365090f,-0.555570233019602f,
                              -0.707106781186548f,-0.831469612302545f,-0.923879532511287f,-0.980785280403230f };
    constexpr float ST[16] = { 0.f, 0.195090322016128f, 0.382683432365090f, 0.555570233019602f,
                               0.707106781186548f, 0.831469612302545f, 0.923879532511287f, 0.980785280403230f,
                               1.f, 0.980785280403230f, 0.923879532511287f, 0.831469612302545f,
                               0.707106781186548f, 0.555570233019602f, 0.382683432365090f, 0.195090322016128f };

    // ---- Pass A: radix-16, stride 512 (input half-zero) ----
    {
        const int j = t;
#pragma unroll
        for (int m=0;m<8;++m){
            const int k  = j + 512*m;          // < 4096 always
            const int ua = s0 + k, ub = ua + BS;
            float va = (ua >= 0) ? xb[ua] : 0.f;
            float vb = (ub >= 0) ? xb[ub] : 0.f;
            d[m] = make_float2(va, vb);
        }
        dft16<false,true>(d);
        float snv, csv; __sincosf(-TWO_PI * (float)j / 8192.f, &snv, &csv);
        twiddle_chain(d, make_float2(csv, snv));
#pragma unroll
        for (int q=0;q<16;++q) sth(buf, j + 512*q, d[q]);
    }
    __syncthreads();

    // ---- Pass B: radix-16, stride 32 ----
    {
        const int base = ((t>>5)<<9) + (t&31);
        const int j = t&31;
#pragma unroll
        for (int m=0;m<16;++m) d[m] = ldh(buf, base + 32*m);
        dft16<false,false>(d);
        float snv, csv; __sincosf(-TWO_PI * (float)j / 512.f, &snv, &csv);
        twiddle_chain(d, make_float2(csv, snv));
#pragma unroll
        for (int q=0;q<16;++q) sth(buf, base + 32*q, d[q]);
    }
    __syncthreads();

    // ---- Pass C: radix-2, stride 16, tw W_32^j on odd output ----
    {
        const int r = t&1, base = 32*(t>>1) + 8*r;
#pragma unroll
        for (int jj=0;jj<8;++jj){
            const int i0 = base + jj;
            const float2 a = ldh(buf, i0), bb = ldh(buf, i0+16);
            const float ck = r ? CT[jj+8] : CT[jj];
            const float sk = r ? ST[jj+8] : ST[jj];
            sth(buf, i0,    cadd(a,bb));
            sth(buf, i0+16, mri(csub(a,bb), ck, -sk));
        }
    }
    __syncthreads();

    // ---- Pass D: DFT16 x Heff x IDFT16, contiguous 16-block ----
    {
        const int base = t<<4;
#pragma unroll
        for (int i=0;i<16;++i) d[i] = ldh(buf, base+i);
        dft16<false,false>(d);
        const float4* H4 = reinterpret_cast<const float4*>(H + (size_t)b*FL + base);
#pragma unroll
        for (int q=0;q<8;++q){
            const float4 hv = H4[q];
            d[2*q]   = cmul(d[2*q],   make_float2(hv.x, hv.y));
            d[2*q+1] = cmul(d[2*q+1], make_float2(hv.z, hv.w));
        }
        dft16<true,false>(d);
#pragma unroll
        for (int i=0;i<16;++i) sth(buf, base+i, d[i]);
    }
    __syncthreads();

    // ---- Pass C': inverse radix-2, stride 16, conj tw before butterfly ----
    {
        const int r = t&1, base = 32*(t>>1) + 8*r;
#pragma unroll
        for (int jj=0;jj<8;++jj){
            const int i0 = base + jj;
            const float2 a = ldh(buf, i0), bb = ldh(buf, i0+16);
            const float ck = r ? CT[jj+8] : CT[jj];
            const float sk = r ? ST[jj+8] : ST[jj];
            const float2 tb = mri(bb, ck, sk);
            sth(buf, i0,    cadd(a,tb));
            sth(buf, i0+16, csub(a,tb));
        }
    }
    __syncthreads();

    // ---- Pass B': inverse radix-16, stride 32 ----
    {
        const int base = ((t>>5)<<9) + (t&31);
        const int j = t&31;
#pragma unroll
        for (int q=0;q<16;++q) d[q] = ldh(buf, base + 32*q);
        float snv, csv; __sincosf(TWO_PI * (float)j / 512.f, &snv, &csv);
        twiddle_chain(d, make_float2(csv, snv));
        dft16<true,false>(d);
#pragma unroll
        for (int m=0;m<16;++m) sth(buf, base + 32*m, d[m]);
    }
    __syncthreads();

    // ---- Pass A': inverse radix-16, stride 512; park time samples in LDS ----
    {
        const int j = t;
#pragma unroll
        for (int q=0;q<16;++q) d[q] = ldh(buf, j + 512*q);
        float snv, csv; __sincosf(TWO_PI * (float)j / 8192.f, &snv, &csv);
        twiddle_chain(d, make_float2(csv, snv));
        dft16<true,false>(d);
    }
    __syncthreads();   // all spec reads done before overwriting with time data
    {
        const int j = t;
#pragma unroll
        for (int m=0;m<16;++m) sth(buf, j + 512*m, d[m]);   // y[time j+512m]
    }
    __syncthreads();

    // ---- Output phase: fully coalesced overlap-add ----
    // klo = t + 512*jj -> lanes 4B-contiguous in every stream.
    {
        float* ob = out + (size_t)b*SEQ;
        const int pa = 2*pr*BS;
#pragma unroll
        for (int jj=0;jj<8;++jj){
            const int klo = t + 512*jj;                      // 0..4095
            const float2 wlo = ldh(buf, klo);                // y[klo]
            const float2 whi = ldh(buf, klo + BS);           // y[klo+4096]
            atomicAdd(&ob[pa+klo], wlo.x);                   // even span (2 writers)
            ob[pa+BS+klo] = whi.x + wlo.y;                   // odd span (sole writer)
            const int p3 = pa + 2*BS + klo;
            if (p3 < SEQ) atomicAdd(&ob[p3], whi.y);         // even span (2 writers)
        }
    }
}

// ---------------------------------------------------------------------------
extern "C" void kernel_launch(void* const* d_in, const int* in_sizes, int n_in,
                              void* d_out, int out_size, void* d_ws, size_t ws_size,
                              hipStream_t stream) {
    const float* x   = (const float*)d_in[0];
    const float* c   = (const float*)d_in[1];
    const float* Wf  = (const float*)d_in[2];
    const float* bfv = (const float*)d_in[3];
    const float* Wp  = (const float*)d_in[4];
    const float* bpv = (const float*)d_in[5];

    float*  out = (float*)d_out;
    float2* H   = (float2*)d_ws;                      // BATCH*FL*8B = 2 MiB

    hipMemsetAsync(d_out, 0, (size_t)out_size*sizeof(float), stream);
    h_kernel<<<dim3(FL/256, BATCH), 256, 0, stream>>>(c, Wf, bfv, Wp, bpv, H);
    fft_kernel<<<dim3(NPAIR, BATCH), 512, FL*sizeof(__half2), stream>>>(x, H, out);
}

// Round 9
// 78.516 us; speedup vs baseline: 2.7315x; 1.2557x over previous
//
#include <hip/hip_runtime.h>
#include <hip/hip_fp16.h>
#include <math.h>

#define FL     8192
#define BS     4096      // block step = FL/2
#define CD     16
#define BATCH  32
#define SEQ    262144
#define NPAIR  32        // 64 blocks -> 32 pairs
#define LDSN   8448      // 8192 + 256 pad (one per 32)

// Packed fp32 complex: <2 x float> -> v_pk_add_f32 / v_pk_fma_f32 on gfx950.
typedef float vf2 __attribute__((ext_vector_type(2)));
__device__ __forceinline__ vf2 mkv(float x, float y){ vf2 v; v.x = x; v.y = y; return v; }
__device__ __forceinline__ vf2 cmul(vf2 a, vf2 b){
    const vf2 c = mkv(-a.y, a.x) * mkv(b.y, b.y);
    return a * mkv(b.x, b.x) + c;
}
__device__ __forceinline__ vf2 mri(vf2 a, float c, float s){   // a * (c + i s)
    const vf2 t = mkv(-a.y, a.x) * mkv(s, s);
    return a * mkv(c, c) + t;
}

// fp16 LDS staging (addresses are PRE-PADDED by caller)
__device__ __forceinline__ void sth(__half2* buf, int i, vf2 v){ buf[i] = __floats2half2_rn(v.x, v.y); }
__device__ __forceinline__ vf2 ldh(const __half2* buf, int i){ const float2 f = __half22float2(buf[i]); return mkv(f.x, f.y); }

// Digit-reversed bin stored at position p after DIF passes
// A(R16,s512), B(R16,s32), C(R2,s16), D(R16,s1):
// k = qA + 16*qB + 256*qC + 512*qD ; p = 512*qA + 32*qB + 16*qC + qD
__device__ __forceinline__ int bin_of_pos(int p){
    return ((p>>9)&15) | (((p>>5)&15)<<4) | (((p>>4)&1)<<8) | ((p&15)<<9);
}

// ---------------------------------------------------------------------------
// In-register 16-point DFT, natural order in/out, 4x4 Cooley-Tukey.
// INV: conjugate (inverse, unnormalized). HALF: inputs d[8..15] are zero.
// ---------------------------------------------------------------------------
template<bool INV, bool HALF>
__device__ __forceinline__ void dft16(vf2* d){
    constexpr float sgn = INV ? 1.f : -1.f;          // e^{sgn*i*2pi*k/16}
    constexpr float C1 = 0.923879532511287f;          // cos(pi/8)
    constexpr float S1 = 0.382683432365090f;          // sin(pi/8)
    constexpr float R  = 0.707106781186548f;
    vf2 u[16];
#pragma unroll
    for (int b=0;b<4;++b){
        const vf2 a0=d[b], a1=d[4+b];
        if (HALF){
            const vf2 ja1 = mkv(-sgn*a1.y, sgn*a1.x);
            u[4*b+0]=a0+a1;
            u[4*b+1]=a0+ja1;
            u[4*b+2]=a0-a1;
            u[4*b+3]=a0-ja1;
        } else {
            const vf2 a2=d[8+b], a3=d[12+b];
            const vf2 s0=a0+a2, s1=a0-a2;
            const vf2 s2=a1+a3, s3=a1-a3;
            const vf2 js3 = mkv(-sgn*s3.y, sgn*s3.x);
            u[4*b+0]=s0+s2;
            u[4*b+1]=s1+js3;
            u[4*b+2]=s0-s2;
            u[4*b+3]=s1-js3;
        }
    }
    u[4+1] = mri(u[4+1],  C1, sgn*S1);
    u[4+2] = mri(u[4+2],  R,  sgn*R );
    u[4+3] = mri(u[4+3],  S1, sgn*C1);
    u[8+1] = mri(u[8+1],  R,  sgn*R );
    u[8+2] = mri(u[8+2],  0.f, sgn);
    u[8+3] = mri(u[8+3], -R,  sgn*R );
    u[12+1]= mri(u[12+1], S1, sgn*C1);
    u[12+2]= mri(u[12+2],-R,  sgn*R );
    u[12+3]= mri(u[12+3],-C1,-sgn*S1);
#pragma unroll
    for (int c=0;c<4;++c){
        const vf2 a0=u[c], a1=u[4+c], a2=u[8+c], a3=u[12+c];
        const vf2 s0=a0+a2, s1=a0-a2;
        const vf2 s2=a1+a3, s3=a1-a3;
        const vf2 js3 = mkv(-sgn*s3.y, sgn*s3.x);
        d[c+0] =s0+s2;
        d[c+4] =s1+js3;
        d[c+8] =s0-s2;
        d[c+12]=s1-js3;
    }
}

// chained twiddle: d[q] *= w1^q, q=1..15
__device__ __forceinline__ void twiddle_chain(vf2* d, vf2 w1){
    vf2 wq = w1;
    d[1] = cmul(d[1], wq);
#pragma unroll
    for (int q=2;q<16;++q){ wq = cmul(wq, w1); d[q] = cmul(d[q], wq); }
}

// ---------------------------------------------------------------------------
// Heff per (batch, position): Heff[f] = (H[f] + conj(H[(N-f)%N]))/2 / N,
// stored at digit-reversed position p (natural/unpadded global array).
// ---------------------------------------------------------------------------
__global__ void h_kernel(const float* __restrict__ c,  const float* __restrict__ Wf,
                         const float* __restrict__ bfv, const float* __restrict__ Wp,
                         const float* __restrict__ bpv, float2* __restrict__ H){
    const int p = blockIdx.x*256 + threadIdx.x;
    const int b = blockIdx.y;
    const int f = bin_of_pos(p);
    const int g = (FL - f) & (FL - 1);
    float amf = bfv[f], apf = bpv[f], amg = bfv[g], apg = bpv[g];
#pragma unroll
    for (int i=0;i<CD;++i){
        const float cv = c[b*CD + i];
        amf += cv * Wf[f*CD + i];
        apf += cv * Wp[f*CD + i];
        amg += cv * Wf[g*CD + i];
        apg += cv * Wp[g*CD + i];
    }
    const float magf = 1.f/(1.f+__expf(-amf));
    const float magg = 1.f/(1.f+__expf(-amg));
    float sf, cf2, sg, cg2;
    __sincosf(apf, &sf, &cf2);
    __sincosf(apg, &sg, &cg2);
    const float scale = 0.5f / (float)FL;
    H[(size_t)b*FL + p] = make_float2((magf*cf2 + magg*cg2)*scale,
                                      (magf*sf  - magg*sg )*scale);
}

// ---------------------------------------------------------------------------
// One WG (512 thr) per (block-pair, batch). Register-resident mixed-radix FFT,
// fp16 LDS staging with PAD-PER-32 layout (addr = i + (i>>5)): per-pass hoisted
// base 'a0' + compile-time offsets -> ds offsets fold to immediates (r8: the
// XOR swizzle cost ~720 VALU/thread). All passes verified 2-way-bank (free).
// __launch_bounds__(512,4): r5/r8-proven 64 VGPR, zero spill (6/8 force spills).
// ---------------------------------------------------------------------------
__global__ __launch_bounds__(512, 4) void fft_kernel(const float*  __restrict__ x,
                                                     const float2* __restrict__ H,
                                                     float* __restrict__ out){
    extern __shared__ __half2 buf[];     // 8448 * 4B = 33 KiB
    const int t  = threadIdx.x;
    const int pr = blockIdx.x;
    const int b  = blockIdx.y;
    const float* xb = x + (size_t)b*SEQ;
    const int s0 = 2*pr*BS - (FL-1);
    const float TWO_PI = 6.28318530717958647692f;

    vf2 d[16];

    constexpr float CT[16] = { 1.f, 0.980785280403230f, 0.923879532511287f, 0.831469612302545f,
                               0.707106781186548f, 0.555570233019602f, 0.382683432365090f, 0.195090322016128f,
                               0.f,-0.195090322016128f,-0.382683432365090f,-0.555570233019602f,
                              -0.707106781186548f,-0.831469612302545f,-0.923879532511287f,-0.980785280403230f };
    constexpr float ST[16] = { 0.f, 0.195090322016128f, 0.382683432365090f, 0.555570233019602f,
                               0.707106781186548f, 0.831469612302545f, 0.923879532511287f, 0.980785280403230f,
                               1.f, 0.980785280403230f, 0.923879532511287f, 0.831469612302545f,
                               0.707106781186548f, 0.555570233019602f, 0.382683432365090f, 0.195090322016128f };

    // ---- Pass A: radix-16, stride 512 (input half-zero) ----
    {
        const int j = t;
#pragma unroll
        for (int m=0;m<8;++m){
            const int k  = j + 512*m;          // < 4096 always
            const int ua = s0 + k, ub = ua + BS;
            const float va = (ua >= 0) ? xb[ua] : 0.f;
            const float vb = (ub >= 0) ? xb[ub] : 0.f;
            d[m] = mkv(va, vb);
        }
        dft16<false,true>(d);
        float snv, csv; __sincosf(-TWO_PI * (float)j / 8192.f, &snv, &csv);
        twiddle_chain(d, mkv(csv, snv));
        const int a0 = j + (j>>5);             // PA(j); offsets 528*q constant
#pragma unroll
        for (int q=0;q<16;++q) sth(buf, a0 + 528*q, d[q]);
    }
    __syncthreads();

    // ---- Pass B: radix-16, stride 32 ----
    {
        const int base = ((t>>5)<<9) + (t&31);
        const int j = t&31;
        const int a0 = base + (base>>5);       // PA(base); offsets 33*m constant
#pragma unroll
        for (int m=0;m<16;++m) d[m] = ldh(buf, a0 + 33*m);
        dft16<false,false>(d);
        float snv, csv; __sincosf(-TWO_PI * (float)j / 512.f, &snv, &csv);
        twiddle_chain(d, mkv(csv, snv));
#pragma unroll
        for (int q=0;q<16;++q) sth(buf, a0 + 33*q, d[q]);
    }
    __syncthreads();

    // ---- Pass C: radix-2, stride 16, tw W_32^j on odd output ----
    {
        const int r = t&1, base = 32*(t>>1) + 8*r;
        const int a0 = base + (t>>1);          // PA(base); (8r+jj(+16)) < 32, no carry
#pragma unroll
        for (int jj=0;jj<8;++jj){
            const vf2 a  = ldh(buf, a0 + jj);
            const vf2 bb = ldh(buf, a0 + jj + 16);
            const float ck = r ? CT[jj+8] : CT[jj];
            const float sk = r ? ST[jj+8] : ST[jj];
            sth(buf, a0 + jj,      a + bb);
            sth(buf, a0 + jj + 16, mri(a - bb, ck, -sk));
        }
    }
    __syncthreads();

    // ---- Pass D: DFT16 x Heff x IDFT16, contiguous 16-block ----
    {
        const int a0 = (t<<4) + (t>>1);        // PA(16t); offsets i < 16
#pragma unroll
        for (int i=0;i<16;++i) d[i] = ldh(buf, a0 + i);
        dft16<false,false>(d);
        const float4* H4 = reinterpret_cast<const float4*>(H + (size_t)b*FL + (t<<4));
#pragma unroll
        for (int q=0;q<8;++q){
            const float4 hv = H4[q];
            d[2*q]   = cmul(d[2*q],   mkv(hv.x, hv.y));
            d[2*q+1] = cmul(d[2*q+1], mkv(hv.z, hv.w));
        }
        dft16<true,false>(d);
#pragma unroll
        for (int i=0;i<16;++i) sth(buf, a0 + i, d[i]);
    }
    __syncthreads();

    // ---- Pass C': inverse radix-2, stride 16, conj tw before butterfly ----
    {
        const int r = t&1, base = 32*(t>>1) + 8*r;
        const int a0 = base + (t>>1);
#pragma unroll
        for (int jj=0;jj<8;++jj){
            const vf2 a  = ldh(buf, a0 + jj);
            const vf2 bb = ldh(buf, a0 + jj + 16);
            const float ck = r ? CT[jj+8] : CT[jj];
            const float sk = r ? ST[jj+8] : ST[jj];
            const vf2 tb = mri(bb, ck, sk);
            sth(buf, a0 + jj,      a + tb);
            sth(buf, a0 + jj + 16, a - tb);
        }
    }
    __syncthreads();

    // ---- Pass B': inverse radix-16, stride 32 ----
    {
        const int base = ((t>>5)<<9) + (t&31);
        const int j = t&31;
        const int a0 = base + (base>>5);
#pragma unroll
        for (int q=0;q<16;++q) d[q] = ldh(buf, a0 + 33*q);
        float snv, csv; __sincosf(TWO_PI * (float)j / 512.f, &snv, &csv);
        twiddle_chain(d, mkv(csv, snv));
        dft16<true,false>(d);
#pragma unroll
        for (int m=0;m<16;++m) sth(buf, a0 + 33*m, d[m]);
    }
    __syncthreads();

    // ---- Pass A': inverse radix-16, stride 512 ----
    {
        const int j = t;
        const int a0 = j + (j>>5);
#pragma unroll
        for (int q=0;q<16;++q) d[q] = ldh(buf, a0 + 528*q);
        float snv, csv; __sincosf(TWO_PI * (float)j / 8192.f, &snv, &csv);
        twiddle_chain(d, mkv(csv, snv));
        dft16<true,false>(d);
    }
    __syncthreads();   // all spectral reads done before overwriting with time data
    // park time sample j+512m at natural index 16j+m -> padded 16j+(j>>1)+m
    {
        const int a0 = (t<<4) + (t>>1);
#pragma unroll
        for (int m=0;m<16;++m) sth(buf, a0 + m, d[m]);
    }
    __syncthreads();

    // ---- Output phase: fully coalesced overlap-add ----
    // sample klo = t + 512*jj lives at park index 16t + jj (padded a0 + jj);
    // sample klo+4096 at a0 + jj + 8. Lanes 4B-contiguous in every stream.
    {
        float* ob = out + (size_t)b*SEQ;
        const int pa = 2*pr*BS;
        const int a0 = (t<<4) + (t>>1);
#pragma unroll
        for (int jj=0;jj<8;++jj){
            const int klo = t + 512*jj;                      // 0..4095
            const vf2 wlo = ldh(buf, a0 + jj);               // y[klo]
            const vf2 whi = ldh(buf, a0 + jj + 8);           // y[klo+4096]
            atomicAdd(&ob[pa+klo], wlo.x);                   // even span (2 writers)
            ob[pa+BS+klo] = whi.x + wlo.y;                   // odd span (sole writer)
            const int p3 = pa + 2*BS + klo;
            if (p3 < SEQ) atomicAdd(&ob[p3], whi.y);         // even span (2 writers)
        }
    }
}

// ---------------------------------------------------------------------------
extern "C" void kernel_launch(void* const* d_in, const int* in_sizes, int n_in,
                              void* d_out, int out_size, void* d_ws, size_t ws_size,
                              hipStream_t stream) {
    const float* x   = (const float*)d_in[0];
    const float* c   = (const float*)d_in[1];
    const float* Wf  = (const float*)d_in[2];
    const float* bfv = (const float*)d_in[3];
    const float* Wp  = (const float*)d_in[4];
    const float* bpv = (const float*)d_in[5];

    float*  out = (float*)d_out;
    float2* H   = (float2*)d_ws;                      // BATCH*FL*8B = 2 MiB

    hipMemsetAsync(d_out, 0, (size_t)out_size*sizeof(float), stream);
    h_kernel<<<dim3(FL/256, BATCH), 256, 0, stream>>>(c, Wf, bfv, Wp, bpv, H);
    fft_kernel<<<dim3(NPAIR, BATCH), 512, LDSN*sizeof(__half2), stream>>>(x, H, out);
}